// Round 3
// baseline (106.882 us; speedup 1.0000x reference)
//
#include <hip/hip_runtime.h>
#include <math.h>

// SpanConsistencyLayer: out = scores + gamma * max(masked, max_{w=2..15} ww[w-2] * bestmin_w)
// bestmin_w(p) = max over windows of width w containing p of min(masked over window).
//
// Identity used (all static indexing, register-only inner loops):
//   A'[0]=B'[0]=v_p; A'[j]=min(A'[j-1], v[p-j]); B'[k]=min(B'[k-1], v[p+k])
//   bestmin[t] = max_{j=0..t} min(A'[j], B'[t-j])      (t = w-1, w = 2..15)
// Out-of-row positions are -inf, which exactly kills invalid (j,k) splits.

constexpr float NEGV = -1.0e9f;
constexpr int W = 15;            // width_logits size
constexpr int HALO = 16;         // padded halo (needs >= 14; 16 for b128 alignment)
constexpr int TPT = 4;           // tokens per thread
constexpr int BLK = 256;         // threads per block
constexpr int TOKS = BLK * TPT;  // tokens per block = 1024
constexpr int TILE_F = TOKS + 2 * HALO;      // 1056 floats
constexpr int TILE_F4 = TILE_F / 4;          // 264 float4

__global__ __launch_bounds__(BLK)
void span_boost_kernel(const float* __restrict__ scores,
                       const int* __restrict__ mask,
                       const float* __restrict__ gamma_p,
                       const float* __restrict__ wlogits,
                       float* __restrict__ out,
                       int N, int chunksPerRow) {
    __shared__ __align__(16) float tile[TILE_F];
    __shared__ float wwS[W];

    const int tid = threadIdx.x;
    const int blk = blockIdx.x;
    const int row = blk / chunksPerRow;
    const int c0 = (blk - row * chunksPerRow) * TOKS;   // first token of this block
    const size_t rowOff = (size_t)row * (size_t)N;
    const float4* s4row = (const float4*)(scores + rowOff);
    const int4*   m4row = (const int4*)(mask + rowOff);

    // 15-way softmax once per block (thread 0), overlapped with staging.
    if (tid == 0) {
        float m = wlogits[0];
        #pragma unroll
        for (int i = 1; i < W; ++i) m = fmaxf(m, wlogits[i]);
        float e[W]; float s = 0.f;
        #pragma unroll
        for (int i = 0; i < W; ++i) { e[i] = expf(wlogits[i] - m); s += e[i]; }
        const float inv = 1.0f / s;
        #pragma unroll
        for (int i = 0; i < W; ++i) wwS[i] = e[i] * inv;
    }

    // Stage masked values (float4 granularity) with halo; outside row = -inf.
    const int g4base = c0 / 4 - HALO / 4;   // float4 index of tile[0]
    const int n4 = N / 4;
    #pragma unroll
    for (int l = tid; l < TILE_F4; l += BLK) {
        const int g4 = g4base + l;
        float4 v = make_float4(-INFINITY, -INFINITY, -INFINITY, -INFINITY);
        if (g4 >= 0 && g4 < n4) {
            const float4 sc = s4row[g4];
            const int4   mk = m4row[g4];
            v.x = (mk.x == 0) ? NEGV : sc.x;
            v.y = (mk.y == 0) ? NEGV : sc.y;
            v.z = (mk.z == 0) ? NEGV : sc.z;
            v.w = (mk.w == 0) ? NEGV : sc.w;
        }
        ((float4*)tile)[l] = v;
    }

    __syncthreads();

    // Wave-uniform softmax weights in SGPRs.
    float ww[W - 1];
    #pragma unroll
    for (int i = 0; i < W - 1; ++i)
        ww[i] = __int_as_float(__builtin_amdgcn_readfirstlane(__float_as_int(wwS[i])));

    // Each thread: 4 consecutive tokens, 36-float register window via 9 aligned b128.
    const int fb = tid * TPT;               // tile float index of (first token - HALO)
    float w[36];
    #pragma unroll
    for (int q = 0; q < 9; ++q) {
        const float4 v = *(const float4*)&tile[fb + 4 * q];
        w[4 * q + 0] = v.x; w[4 * q + 1] = v.y; w[4 * q + 2] = v.z; w[4 * q + 3] = v.w;
    }
    // w[i] = masked[c0 - 16 + 4*tid + i]; token r sits at w[16 + r].

    const int gp4 = c0 / 4 + tid;           // float4 index of this thread's 4 tokens
    const float4 sc4 = s4row[gp4];
    const float myScore[TPT] = { sc4.x, sc4.y, sc4.z, sc4.w };
    const float gamma = gamma_p[0];

    float res[TPT];
    #pragma unroll
    for (int r = 0; r < TPT; ++r) {
        const float vp = w[16 + r];
        float Ap[W], Bp[W];
        Ap[0] = vp; Bp[0] = vp;
        #pragma unroll
        for (int j = 1; j < W; ++j) Ap[j] = fminf(Ap[j - 1], w[16 + r - j]);
        #pragma unroll
        for (int k = 1; k < W; ++k) Bp[k] = fminf(Bp[k - 1], w[16 + r + k]);

        float boost = -INFINITY;
        #pragma unroll
        for (int t = 1; t <= W - 1; ++t) {
            float d = fmaxf(Ap[t], Bp[t]);          // j=t and j=0 splits
            #pragma unroll
            for (int j = 1; j < t; ++j)
                d = fmaxf(d, fminf(Ap[j], Bp[t - j]));
            boost = fmaxf(boost, d * ww[t - 1]);
        }
        res[r] = myScore[r] + gamma * fmaxf(boost, vp);
    }

    float4 o4 = make_float4(res[0], res[1], res[2], res[3]);
    ((float4*)(out + rowOff))[gp4] = o4;
}

extern "C" void kernel_launch(void* const* d_in, const int* in_sizes, int n_in,
                              void* d_out, int out_size, void* d_ws, size_t ws_size,
                              hipStream_t stream) {
    const float* scores = (const float*)d_in[0];
    const int*   maskp  = (const int*)d_in[1];
    const float* gammap = (const float*)d_in[2];
    const float* wl     = (const float*)d_in[3];
    float* outp = (float*)d_out;

    const int N = 8192;                     // per reference setup
    const int B = in_sizes[0] / N;          // 512
    const int chunksPerRow = N / TOKS;      // 8
    dim3 grid(B * chunksPerRow);
    span_boost_kernel<<<grid, BLK, 0, stream>>>(scores, maskp, gammap, wl, outp,
                                                N, chunksPerRow);
}

// Round 4
// 98.803 us; speedup vs baseline: 1.0818x; 1.0818x over previous
//
#include <hip/hip_runtime.h>
#include <math.h>

// SpanConsistencyLayer: out = scores + gamma * max(masked, max_{w=2..15} ww[w-2] * bestmin_w)
// bestmin_w(p) = max over windows of width w containing p of min(masked over window).
//
// Identities (all static register indexing):
//   Ap[j] = min(masked[p-j..p]), Bp[k] = min(masked[p..p+k])   (both sorted desc)
//   bestmin[t] = max_{j+k=t} min(Ap[j], Bp[k])
//              = t-th element of the DESCENDING MERGE of Ap[1..14] and Bp[1..14]
//   (greedy pick-larger-head == descending merge; every element <= vp).
// Merge computed with a bitonic merge network: pad to 32 as (desc ++ asc),
// half-cleaner, then 16-wide bitonic sort. Out-of-row = -inf kills bad splits.

constexpr float NEGV = -1.0e9f;
constexpr int W = 15;            // width_logits size
constexpr int HALO = 16;         // padded halo (needs >= 14; 16 for b128 alignment)
constexpr int TPT = 4;           // tokens per thread
constexpr int BLK = 256;         // threads per block
constexpr int TOKS = BLK * TPT;  // tokens per block = 1024
constexpr int TILE_F = TOKS + 2 * HALO;      // 1056 floats
constexpr int TILE_F4 = TILE_F / 4;          // 264 float4

__global__ __launch_bounds__(BLK)
void span_boost_kernel(const float* __restrict__ scores,
                       const int* __restrict__ mask,
                       const float* __restrict__ gamma_p,
                       const float* __restrict__ wlogits,
                       float* __restrict__ out,
                       int N, int chunksPerRow) {
    __shared__ __align__(16) float tile[TILE_F];
    __shared__ float wwS[W];

    const int tid = threadIdx.x;
    const int blk = blockIdx.x;
    const int row = blk / chunksPerRow;
    const int c0 = (blk - row * chunksPerRow) * TOKS;   // first token of this block
    const size_t rowOff = (size_t)row * (size_t)N;
    const float4* s4row = (const float4*)(scores + rowOff);
    const int4*   m4row = (const int4*)(mask + rowOff);

    // 15-way softmax once per block (thread 0), overlapped with staging.
    if (tid == 0) {
        float m = wlogits[0];
        #pragma unroll
        for (int i = 1; i < W; ++i) m = fmaxf(m, wlogits[i]);
        float e[W]; float s = 0.f;
        #pragma unroll
        for (int i = 0; i < W; ++i) { e[i] = expf(wlogits[i] - m); s += e[i]; }
        const float inv = 1.0f / s;
        #pragma unroll
        for (int i = 0; i < W; ++i) wwS[i] = e[i] * inv;
    }

    // Stage masked values (float4 granularity) with halo; outside row = -inf.
    const int g4base = c0 / 4 - HALO / 4;   // float4 index of tile[0]
    const int n4 = N / 4;
    #pragma unroll
    for (int l = tid; l < TILE_F4; l += BLK) {
        const int g4 = g4base + l;
        float4 v = make_float4(-INFINITY, -INFINITY, -INFINITY, -INFINITY);
        if (g4 >= 0 && g4 < n4) {
            const float4 sc = s4row[g4];
            const int4   mk = m4row[g4];
            v.x = (mk.x == 0) ? NEGV : sc.x;
            v.y = (mk.y == 0) ? NEGV : sc.y;
            v.z = (mk.z == 0) ? NEGV : sc.z;
            v.w = (mk.w == 0) ? NEGV : sc.w;
        }
        ((float4*)tile)[l] = v;
    }

    __syncthreads();

    // Wave-uniform softmax weights in SGPRs (only indices 0..13 are used by ref).
    float ww[W - 1];
    #pragma unroll
    for (int i = 0; i < W - 1; ++i)
        ww[i] = __int_as_float(__builtin_amdgcn_readfirstlane(__float_as_int(wwS[i])));

    // Each thread: 4 consecutive tokens, 36-float register window via 9 aligned b128.
    const int fb = tid * TPT;               // tile float index of (first token - HALO)
    float w[36];
    #pragma unroll
    for (int q = 0; q < 9; ++q) {
        const float4 v = *(const float4*)&tile[fb + 4 * q];
        w[4 * q + 0] = v.x; w[4 * q + 1] = v.y; w[4 * q + 2] = v.z; w[4 * q + 3] = v.w;
    }
    // w[i] = masked[c0 - 16 + 4*tid + i]; token r sits at w[16 + r].

    const int gp4 = c0 / 4 + tid;           // float4 index of this thread's 4 tokens
    const float4 sc4 = s4row[gp4];
    const float myScore[TPT] = { sc4.x, sc4.y, sc4.z, sc4.w };
    const float gamma = gamma_p[0];

    float res[TPT];
    #pragma unroll
    for (int r = 0; r < TPT; ++r) {
        const int c = 16 + r;
        const float vp = w[c];
        float Ap[W], Bp[W];
        Ap[0] = vp; Bp[0] = vp;
        #pragma unroll
        for (int j = 1; j < W; ++j) {
            Ap[j] = fminf(Ap[j - 1], w[c - j]);
            Bp[j] = fminf(Bp[j - 1], w[c + j]);
        }

        // Half-cleaner of the 32-bitonic (Ap[1..14],-inf,-inf, -inf,-inf,Bp[14..1]):
        float s[16];
        s[0] = Ap[1]; s[1] = Ap[2];
        #pragma unroll
        for (int i = 2; i <= 13; ++i) s[i] = fmaxf(Ap[i + 1], Bp[16 - i]);
        s[14] = Bp[2]; s[15] = Bp[1];

        // Descending bitonic sort of the 16 survivors (top-16 of the merge).
        #pragma unroll
        for (int d = 8; d >= 1; d >>= 1) {
            #pragma unroll
            for (int i = 0; i < 16; ++i) {
                if (!(i & d)) {
                    const float a = s[i], b = s[i | d];
                    s[i] = fmaxf(a, b);       // descending: max on top
                    s[i | d] = fminf(a, b);
                }
            }
        }
        // s[t-1] = bestmin for width w = t+1, weight index t-1.
        float boost = ww[0] * s[0];
        #pragma unroll
        for (int i = 1; i < 14; ++i) boost = fmaxf(boost, ww[i] * s[i]);

        res[r] = myScore[r] + gamma * fmaxf(boost, vp);
    }

    float4 o4 = make_float4(res[0], res[1], res[2], res[3]);
    ((float4*)(out + rowOff))[gp4] = o4;
}

extern "C" void kernel_launch(void* const* d_in, const int* in_sizes, int n_in,
                              void* d_out, int out_size, void* d_ws, size_t ws_size,
                              hipStream_t stream) {
    const float* scores = (const float*)d_in[0];
    const int*   maskp  = (const int*)d_in[1];
    const float* gammap = (const float*)d_in[2];
    const float* wl     = (const float*)d_in[3];
    float* outp = (float*)d_out;

    const int N = 8192;                     // per reference setup
    const int B = in_sizes[0] / N;          // 512
    const int chunksPerRow = N / TOKS;      // 8
    dim3 grid(B * chunksPerRow);
    span_boost_kernel<<<grid, BLK, 0, stream>>>(scores, maskp, gammap, wl, outp,
                                                N, chunksPerRow);
}